// Round 1
// baseline (698.467 us; speedup 1.0000x reference)
//
#include <hip/hip_runtime.h>
#include <hip/hip_bf16.h>
#include <float.h>

#define N_PART 262144
#define GRID_DIM 256
#define NUM_CELLS (GRID_DIM * GRID_DIM)
#define KSLOT 32
#define MAXNB 64

// ---------------- ws layout ----------------
// [0..255]                         : params (uint bits: minx, miny, maxh)
// [256 .. 256+NUM_CELLS*4)         : counts (int per cell)
// next ((NUM_CELLS+1)*KSLOT*4)     : table  (int slots, -1 = empty)
// next (N*4)                       : lin per particle

__global__ void init_params(unsigned int* params) {
    params[0] = 0x7f7fffffu;  // FLT_MAX bits (min x)
    params[1] = 0x7f7fffffu;  // FLT_MAX bits (min y)
    params[2] = 0u;           // 0.0f       (max h)
}

__global__ void reduce_kernel(const float* __restrict__ pos,
                              const float* __restrict__ sup,
                              unsigned int* params, int n) {
    __shared__ unsigned int s_minx, s_miny, s_maxh;
    if (threadIdx.x == 0) { s_minx = 0x7f7fffffu; s_miny = 0x7f7fffffu; s_maxh = 0u; }
    __syncthreads();
    float mx = FLT_MAX, my = FLT_MAX, mh = 0.0f;
    for (int i = blockIdx.x * blockDim.x + threadIdx.x; i < n;
         i += gridDim.x * blockDim.x) {
        float x = pos[2 * i], y = pos[2 * i + 1], h = sup[i];
        mx = fminf(mx, x);
        my = fminf(my, y);
        mh = fmaxf(mh, h);
    }
    // non-negative floats: uint compare == float compare
    atomicMin(&s_minx, __float_as_uint(mx));
    atomicMin(&s_miny, __float_as_uint(my));
    atomicMax(&s_maxh, __float_as_uint(mh));
    __syncthreads();
    if (threadIdx.x == 0) {
        atomicMin(&params[0], s_minx);
        atomicMin(&params[1], s_miny);
        atomicMax(&params[2], s_maxh);
    }
}

__global__ void bin_kernel(const float* __restrict__ pos,
                           const unsigned int* __restrict__ params,
                           int* __restrict__ counts, int* __restrict__ table,
                           int* __restrict__ lin_out, int n) {
    int i = blockIdx.x * blockDim.x + threadIdx.x;
    if (i >= n) return;
    float hmax  = __uint_as_float(params[2]);
    float qminx = __uint_as_float(params[0]) - hmax;
    float qminy = __uint_as_float(params[1]) - hmax;
    float x = pos[2 * i], y = pos[2 * i + 1];
    int cx = (int)ceilf((x - qminx) / hmax);
    int cy = (int)ceilf((y - qminy) / hmax);
    cx = min(max(cx, 0), GRID_DIM - 1);
    cy = min(max(cy, 0), GRID_DIM - 1);
    int lin = cx + GRID_DIM * cy;
    lin_out[i] = lin;
    int slot = atomicAdd(&counts[lin], 1);
    if (slot < KSLOT) table[lin * KSLOT + slot] = i;
    // rank >= KSLOT: reference drops these into the (never-matched in
    // practice) overflow row; Poisson(4) makes count>32 impossible here.
}

__global__ void sort_kernel(const int* __restrict__ counts, int* __restrict__ table) {
    int c = blockIdx.x * blockDim.x + threadIdx.x;
    if (c >= NUM_CELLS) return;
    int cnt = counts[c];
    if (cnt > KSLOT) cnt = KSLOT;
    int* row = table + c * KSLOT;
    // restore ascending-particle-index order (stable argsort semantics)
    for (int a = 1; a < cnt; a++) {
        int v = row[a];
        int b = a - 1;
        while (b >= 0 && row[b] > v) { row[b + 1] = row[b]; b--; }
        row[b + 1] = v;
    }
}

__global__ void query_kernel(const float* __restrict__ pos,
                             const float* __restrict__ sup,
                             const int* __restrict__ lin,
                             const int* __restrict__ table,
                             float* __restrict__ outN, float* __restrict__ outC,
                             float* __restrict__ outR, int n) {
#pragma clang fp contract(off)
    int i = blockIdx.x * blockDim.x + threadIdx.x;
    if (i >= n) return;
    const float2* pos2 = (const float2*)pos;
    float2 p = pos2[i];
    float h = sup[i];
    int L = lin[i];
    // reference candidate-cell order: (dx,dy) ij-meshgrid, offs = dx + 256*dy
    const int offs[9] = {-257, -1, 255, -256, 0, 256, -255, 1, 257};
    int cnt = 0, w = 0;
    size_t base = (size_t)i * MAXNB;
    for (int o = 0; o < 9; o++) {
        int cell = L + offs[o];
        cell = min(max(cell, 0), NUM_CELLS);
        const int* row = table + (size_t)cell * KSLOT;
        for (int k = 0; k < KSLOT; k++) {
            int j = row[k];
            if (j < 0) break;  // slots are filled contiguously from 0
            float2 q = pos2[j];
            float dx = q.x - p.x;
            float dy = q.y - p.y;
            float s = dx * dx + dy * dy;  // contract(off): no FMA, match XLA
            float d = sqrtf(s);           // correctly rounded (HIP default)
            if (d <= h) {
                if (w < MAXNB) {
                    outN[base + w] = (float)j;
                    outR[base + w] = d / h;
                    w++;
                }
                cnt++;
            }
        }
    }
    for (int t = w; t < MAXNB; t++) {
        outN[base + t] = -1.0f;
        outR[base + t] = 0.0f;
    }
    outC[i] = (float)cnt;
}

extern "C" void kernel_launch(void* const* d_in, const int* in_sizes, int n_in,
                              void* d_out, int out_size, void* d_ws, size_t ws_size,
                              hipStream_t stream) {
    const float* pos = (const float*)d_in[0];
    const float* sup = (const float*)d_in[1];

    char* ws = (char*)d_ws;
    unsigned int* params = (unsigned int*)ws;
    int* counts = (int*)(ws + 256);
    int* table  = (int*)(ws + 256 + (size_t)NUM_CELLS * 4);
    int* lin    = (int*)(ws + 256 + (size_t)NUM_CELLS * 4 +
                         (size_t)(NUM_CELLS + 1) * KSLOT * 4);

    float* out  = (float*)d_out;
    float* outN = out;                              // N*64 neighbor ids (as f32)
    float* outC = out + (size_t)N_PART * MAXNB;     // N counts
    float* outR = outC + N_PART;                    // N*64 radial

    hipMemsetAsync(table, 0xFF, (size_t)(NUM_CELLS + 1) * KSLOT * 4, stream);
    hipMemsetAsync(counts, 0, (size_t)NUM_CELLS * 4, stream);
    init_params<<<1, 1, 0, stream>>>(params);
    reduce_kernel<<<256, 256, 0, stream>>>(pos, sup, params, N_PART);
    bin_kernel<<<N_PART / 256, 256, 0, stream>>>(pos, params, counts, table, lin, N_PART);
    sort_kernel<<<NUM_CELLS / 256, 256, 0, stream>>>(counts, table);
    query_kernel<<<N_PART / 256, 256, 0, stream>>>(pos, sup, lin, table,
                                                   outN, outC, outR, N_PART);
}

// Round 2
// 332.562 us; speedup vs baseline: 2.1003x; 2.1003x over previous
//
#include <hip/hip_runtime.h>
#include <hip/hip_bf16.h>
#include <float.h>

#define N_PART 262144
#define GRID_DIM 256
#define NUM_CELLS (GRID_DIM * GRID_DIM)
#define KSLOT 32
#define MAXNB 64

// ---------------- ws layout ----------------
// [0..255]                           : params (uint bits: minx, miny, maxh)
// [256 .. 256+(NUM_CELLS+1)*4)       : counts (int per cell, +1 overflow row)
// next ((NUM_CELLS+1)*KSLOT*4)       : table  (int slots, -1 = empty)
// next (N*4)                         : lin per particle

__global__ void init_params(unsigned int* params) {
    params[0] = 0x7f7fffffu;  // FLT_MAX bits (min x)
    params[1] = 0x7f7fffffu;  // FLT_MAX bits (min y)
    params[2] = 0u;           // 0.0f       (max h)
}

__global__ void reduce_kernel(const float* __restrict__ pos,
                              const float* __restrict__ sup,
                              unsigned int* params, int n) {
    __shared__ unsigned int s_minx, s_miny, s_maxh;
    if (threadIdx.x == 0) { s_minx = 0x7f7fffffu; s_miny = 0x7f7fffffu; s_maxh = 0u; }
    __syncthreads();
    float mx = FLT_MAX, my = FLT_MAX, mh = 0.0f;
    for (int i = blockIdx.x * blockDim.x + threadIdx.x; i < n;
         i += gridDim.x * blockDim.x) {
        float x = pos[2 * i], y = pos[2 * i + 1], h = sup[i];
        mx = fminf(mx, x);
        my = fminf(my, y);
        mh = fmaxf(mh, h);
    }
    // non-negative floats: uint compare == float compare
    atomicMin(&s_minx, __float_as_uint(mx));
    atomicMin(&s_miny, __float_as_uint(my));
    atomicMax(&s_maxh, __float_as_uint(mh));
    __syncthreads();
    if (threadIdx.x == 0) {
        atomicMin(&params[0], s_minx);
        atomicMin(&params[1], s_miny);
        atomicMax(&params[2], s_maxh);
    }
}

__global__ void bin_kernel(const float* __restrict__ pos,
                           const unsigned int* __restrict__ params,
                           int* __restrict__ counts, int* __restrict__ table,
                           int* __restrict__ lin_out, int n) {
    int i = blockIdx.x * blockDim.x + threadIdx.x;
    if (i >= n) return;
    float hmax  = __uint_as_float(params[2]);
    float qminx = __uint_as_float(params[0]) - hmax;
    float qminy = __uint_as_float(params[1]) - hmax;
    float x = pos[2 * i], y = pos[2 * i + 1];
    int cx = (int)ceilf((x - qminx) / hmax);
    int cy = (int)ceilf((y - qminy) / hmax);
    cx = min(max(cx, 0), GRID_DIM - 1);
    cy = min(max(cy, 0), GRID_DIM - 1);
    int lin = cx + GRID_DIM * cy;
    lin_out[i] = lin;
    int slot = atomicAdd(&counts[lin], 1);
    if (slot < KSLOT) table[lin * KSLOT + slot] = i;
    // Poisson(4) occupancy: count>32 never happens for this data, so the
    // reference's overflow row stays empty.
}

__global__ void sort_kernel(const int* __restrict__ counts, int* __restrict__ table) {
    int c = blockIdx.x * blockDim.x + threadIdx.x;
    if (c >= NUM_CELLS) return;
    int cnt = counts[c];
    if (cnt > KSLOT) cnt = KSLOT;
    int* row = table + c * KSLOT;
    // restore ascending-particle-index order (stable argsort semantics)
    for (int a = 1; a < cnt; a++) {
        int v = row[a];
        int b = a - 1;
        while (b >= 0 && row[b] > v) { row[b + 1] = row[b]; b--; }
        row[b + 1] = v;
    }
}

// One wave (64 lanes) per particle. Lanes enumerate the 9-cell candidate
// list in the reference's (cell-offset, slot) order; ballot+popc gives the
// stable compaction rank; results staged in per-wave LDS then written with
// fully-coalesced 256B row stores (kills the partial-line RMW thrash that
// caused 909 MB of HBM fetch in the thread-per-particle version).
__global__ void query_wave_kernel(const float* __restrict__ pos,
                                  const float* __restrict__ sup,
                                  const int* __restrict__ lin,
                                  const int* __restrict__ counts,
                                  const int* __restrict__ table,
                                  float* __restrict__ outN, float* __restrict__ outC,
                                  float* __restrict__ outR, int n) {
#pragma clang fp contract(off)
    __shared__ int   s_id[4][MAXNB];   // 4 waves per 256-thread block
    __shared__ float s_d[4][MAXNB];

    int gtid = blockIdx.x * blockDim.x + threadIdx.x;
    int i    = gtid >> 6;          // wave index == particle index
    int lane = threadIdx.x & 63;
    int wsl  = threadIdx.x >> 6;   // wave slot within block
    if (i >= n) return;

    const float2* pos2 = (const float2*)pos;
    float2 p = pos2[i];
    float h = sup[i];
    int L = lin[i];

    // reference candidate-cell order: offs = dx + 256*dy, ij-meshgrid
    const int offs[9] = {-257, -1, 255, -256, 0, 256, -255, 1, 257};
    int cum[10];
    cum[0] = 0;
    for (int o = 0; o < 9; o++) {
        int cell = L + offs[o];
        cell = min(max(cell, 0), NUM_CELLS);
        int c = counts[cell];
        c = min(c, KSLOT);
        cum[o + 1] = cum[o] + c;
    }
    int T = cum[9];

    int total = 0, written = 0;
    for (int b = 0; b < T; b += 64) {
        int ll = b + lane;
        bool active = ll < T;
        int j = 0;
        float d = 0.0f;
        if (active) {
            int o = 0;
            for (int m = 1; m <= 8; m++) o += (ll >= cum[m]);
            int cell = L + offs[o];
            cell = min(max(cell, 0), NUM_CELLS);
            int slot = ll - cum[o];
            j = table[cell * KSLOT + slot];
            float2 q = pos2[j];
            float dx = q.x - p.x;
            float dy = q.y - p.y;
            float s = dx * dx + dy * dy;   // contract(off): no FMA, match XLA
            d = sqrtf(s);                  // correctly rounded
        }
        bool valid = active && (d <= h);
        unsigned long long bal = __ballot(valid);
        int rank = __popcll(bal & ((1ull << lane) - 1ull));
        if (valid) {
            int w = written + rank;
            if (w < MAXNB) {
                s_id[wsl][w] = j;
                s_d[wsl][w]  = d;
            }
        }
        int c = __popcll(bal);
        total   += c;
        written += c;
    }
    // LDS ops from the same wave are processed in order; buffer is
    // wave-private so no barrier needed.
    int stored = min(written, MAXNB);
    size_t base = (size_t)i * MAXNB;
    if (lane < stored) {
        int j   = s_id[wsl][lane];
        float d = s_d[wsl][lane];
        outN[base + lane] = (float)j;
        outR[base + lane] = d / h;
    } else {
        outN[base + lane] = -1.0f;
        outR[base + lane] = 0.0f;
    }
    if (lane == 0) outC[i] = (float)total;
}

extern "C" void kernel_launch(void* const* d_in, const int* in_sizes, int n_in,
                              void* d_out, int out_size, void* d_ws, size_t ws_size,
                              hipStream_t stream) {
    const float* pos = (const float*)d_in[0];
    const float* sup = (const float*)d_in[1];

    char* ws = (char*)d_ws;
    unsigned int* params = (unsigned int*)ws;
    int* counts = (int*)(ws + 256);
    int* table  = (int*)(ws + 256 + (size_t)(NUM_CELLS + 1) * 4);
    int* lin    = (int*)(ws + 256 + (size_t)(NUM_CELLS + 1) * 4 +
                         (size_t)(NUM_CELLS + 1) * KSLOT * 4);

    float* out  = (float*)d_out;
    float* outN = out;                              // N*64 neighbor ids (as f32)
    float* outC = out + (size_t)N_PART * MAXNB;     // N counts
    float* outR = outC + N_PART;                    // N*64 radial

    hipMemsetAsync(table, 0xFF, (size_t)(NUM_CELLS + 1) * KSLOT * 4, stream);
    hipMemsetAsync(counts, 0, (size_t)(NUM_CELLS + 1) * 4, stream);
    init_params<<<1, 1, 0, stream>>>(params);
    reduce_kernel<<<256, 256, 0, stream>>>(pos, sup, params, N_PART);
    bin_kernel<<<N_PART / 256, 256, 0, stream>>>(pos, params, counts, table, lin, N_PART);
    sort_kernel<<<NUM_CELLS / 256, 256, 0, stream>>>(counts, table);
    // one wave per particle: N_PART waves = N_PART*64 threads
    query_wave_kernel<<<(N_PART * 64) / 256, 256, 0, stream>>>(
        pos, sup, lin, counts, table, outN, outC, outR, N_PART);
}